// Round 1
// baseline (233.709 us; speedup 1.0000x reference)
//
#include <hip/hip_runtime.h>
#include <hip/hip_bf16.h>
#include <math.h>

// AttnBlock: B=16, C=256, H=W=64, heads=4, dim_head=32
#define BATCH 16
#define CH 256
#define NPOS 4096
#define INNER 128
#define HEADS 4
#define DH 32

typedef __hip_bfloat16 bf16;
typedef short bf8v __attribute__((ext_vector_type(8)));    // 8 bf16 (4 VGPRs)
typedef float f32x4 __attribute__((ext_vector_type(4)));

__device__ __forceinline__ float b2f(bf16 v) { return __bfloat162float(v); }
__device__ __forceinline__ float us2f(unsigned short u) {
    unsigned w = ((unsigned)u) << 16; float f; __builtin_memcpy(&f, &w, 4); return f;
}
__device__ __forceinline__ unsigned short f2us(float f) {
    bf16 h = __float2bfloat16(f); unsigned short u; __builtin_memcpy(&u, &h, 2); return u;
}
__device__ __forceinline__ bf16 f2b(float v) { return __float2bfloat16(v); }

// ---------------------------------------------------------------------------
// K0: one-shot Wqkv fp32 -> bf16 (same rounding as the old per-block staging).
// 384*256 = 98304 elems, 4/thread, grid 96.
// ---------------------------------------------------------------------------
__global__ __launch_bounds__(256)
void prep_w_kernel(const float* __restrict__ Wqkv, bf16* __restrict__ wqb) {
    int idx = (blockIdx.x * 256 + threadIdx.x) * 4;
    float4 w = *(const float4*)&Wqkv[idx];
    ushort4 u;
    u.x = f2us(w.x); u.y = f2us(w.y); u.z = f2us(w.z); u.w = f2us(w.w);
    *(ushort4*)&wqb[idx] = u;
}

// ---------------------------------------------------------------------------
// K1: fused LN + qkv GEMM + q-softmax.
// grid (32 n-tiles, 16 b), 256 threads. A-tile = LN(x)^T [128 n][256 c] bf16,
// fully LDS-resident. B-fragments are read DIRECTLY from global (wqb bf16,
// 192 KB, L2-resident) -> the k-loop has ZERO barriers and pipelines freely.
// Phases: k (cols 128-255), v (256-383), q (0-127, last so A is dead).
// ---------------------------------------------------------------------------
__global__ __launch_bounds__(256)
void fused_qkv_kernel(const float* __restrict__ x, const bf16* __restrict__ wqb,
                      bf16* __restrict__ p, bf16* __restrict__ kvt) {
    __shared__ bf16 A[128 * 264];      // 67584 B
    __shared__ bf16 Bb[128 * 32];      // 8192 B: kv epilogue transpose tile
    __shared__ float stats[512];       // 2048 B: LN partials -> mu/rs -> rdenom

    const int b = blockIdx.y, n0 = blockIdx.x * 128;
    const int tid = threadIdx.x;
    const int wave = tid >> 6, lane = tid & 63;
    const int wm = (wave >> 1) * 64, wn = (wave & 1) * 64;
    const int lrow = lane & 15, kq = lane >> 4;

    // ---- stage x tile (raw bf16) + per-thread LN partial stats ----
    {
        const int n = tid & 127, chalf = tid >> 7;
        const float* xp = x + ((size_t)b * CH + chalf * 128) * NPOS + n0 + n;
        float s = 0.f, sq = 0.f;
        for (int i0 = 0; i0 < 128; i0 += 8) {
            bf8v bv;
            #pragma unroll
            for (int j = 0; j < 8; ++j) {
                float v = xp[(size_t)(i0 + j) * NPOS];
                s += v; sq += v * v;
                bv[j] = (short)f2us(v);
            }
            *(bf8v*)&A[n * 264 + chalf * 128 + i0] = bv;
        }
        stats[tid * 2] = s; stats[tid * 2 + 1] = sq;
    }
    __syncthreads();
    if (tid < 128) {
        float s  = stats[tid * 2] + stats[(tid + 128) * 2];
        float sq = stats[tid * 2 + 1] + stats[(tid + 128) * 2 + 1];
        float m = s * (1.f / 256.f);
        float var = sq * (1.f / 256.f) - m * m;
        stats[tid * 2] = m;
        stats[tid * 2 + 1] = rsqrtf(var + 1e-5f);
    }
    __syncthreads();
    // ---- normalize A in place (u32 pairs, c-fast, conflict-free) ----
    {
        unsigned* A32 = (unsigned*)A;
        #pragma unroll 4
        for (int i = 0; i < 64; ++i) {
            int idx = i * 256 + tid;
            int c2 = idx & 127, n = idx >> 7;
            unsigned u = A32[n * 132 + c2];
            float m = stats[n * 2], rs = stats[n * 2 + 1];
            float v0 = (us2f((unsigned short)(u & 0xffffu)) - m) * rs;
            float v1 = (us2f((unsigned short)(u >> 16)) - m) * rs;
            A32[n * 132 + c2] = (unsigned)f2us(v0) | ((unsigned)f2us(v1) << 16);
        }
    }
    __syncthreads();   // A normalized and visible; read-only from here (until q dump)

    for (int ph = 0; ph < 3; ++ph) {
        const int colbase = (ph == 2) ? 0 : (ph + 1) * 128;   // k, v, q
        const bf16* wp = wqb + (size_t)colbase * 256;
        f32x4 acc[4][4];
        #pragma unroll
        for (int i = 0; i < 4; ++i)
            #pragma unroll
            for (int j = 0; j < 4; ++j) acc[i][j] = (f32x4){0.f, 0.f, 0.f, 0.f};

        // barrier-free k-loop: A frags from LDS, B frags straight from L2
        #pragma unroll 2
        for (int k0 = 0; k0 < 256; k0 += 32) {
            bf8v af[4], bfr[4];
            #pragma unroll
            for (int t = 0; t < 4; ++t)
                af[t] = *(const bf8v*)&A[(wm + t * 16 + lrow) * 264 + k0 + kq * 8];
            #pragma unroll
            for (int t = 0; t < 4; ++t)
                bfr[t] = *(const bf8v*)&wp[(size_t)(wn + t * 16 + lrow) * 256 + k0 + kq * 8];
            #pragma unroll
            for (int mt = 0; mt < 4; ++mt)
                #pragma unroll
                for (int nt = 0; nt < 4; ++nt)
                    acc[mt][nt] = __builtin_amdgcn_mfma_f32_16x16x32_bf16(
                        af[mt], bfr[nt], acc[mt][nt], 0, 0, 0);
        }

        if (ph < 2) {
            // k/v epilogue: 4 row-passes of 32 via Bb for coalesced stores
            unsigned* B32 = (unsigned*)Bb;
            unsigned* kv32 = (unsigned*)kvt;
            for (int pr = 0; pr < 4; ++pr) {
                __syncthreads();
                if ((wave >> 1) == (pr >> 1)) {
                    int mtb = (pr & 1) * 2;
                    #pragma unroll
                    for (int mi = 0; mi < 2; ++mi) {
                        int mt = mtb + mi;
                        #pragma unroll
                        for (int nt = 0; nt < 4; ++nt)
                            #pragma unroll
                            for (int r = 0; r < 4; ++r) {
                                int rl = mi * 16 + kq * 4 + r;       // 0..31
                                Bb[rl * 128 + wn + nt * 16 + lrow] = f2b(acc[mt][nt][r]);
                            }
                    }
                }
                __syncthreads();
                #pragma unroll
                for (int i = 0; i < 8; ++i) {
                    int idx = i * 256 + tid;     // 2048 u32
                    int c2 = idx & 63, rl = idx >> 6;
                    kv32[(size_t)(b * NPOS + n0 + pr * 32 + rl) * 128 + ph * 64 + c2] =
                        B32[rl * 64 + c2];
                }
            }
        } else {
            // q epilogue: dump raw accs over A, softmax per (row, head), store p
            __syncthreads();
            bf16* pt = A;                        // [128][132]
            #pragma unroll
            for (int mt = 0; mt < 4; ++mt)
                #pragma unroll
                for (int nt = 0; nt < 4; ++nt)
                    #pragma unroll
                    for (int r = 0; r < 4; ++r)
                        pt[(wm + mt * 16 + kq * 4 + r) * 132 + wn + nt * 16 + lrow] =
                            f2b(acc[mt][nt][r]);
            __syncthreads();
            {   // reciprocal softmax denominators (no max-sub: |q| < ~6 -> safe)
                int row = tid >> 1, hp = (tid & 1) * 2;
                float s0 = 0.f, s1 = 0.f;
                #pragma unroll 8
                for (int j = 0; j < 32; ++j) s0 += __expf(b2f(pt[row * 132 + hp * 32 + j]));
                #pragma unroll 8
                for (int j = 0; j < 32; ++j) s1 += __expf(b2f(pt[row * 132 + hp * 32 + 32 + j]));
                stats[row * 4 + hp] = 1.f / s0;
                stats[row * 4 + hp + 1] = 1.f / s1;
            }
            __syncthreads();
            unsigned* pt32 = (unsigned*)pt;
            unsigned* pg32 = (unsigned*)p;
            #pragma unroll 4
            for (int i = 0; i < 32; ++i) {
                int idx = i * 256 + tid;         // 8192 u32
                int c2 = idx & 63, n = idx >> 6;
                unsigned u = pt32[n * 66 + c2];
                float rd = stats[n * 4 + (c2 >> 4)];
                float v0 = __expf(us2f((unsigned short)(u & 0xffffu))) * rd;
                float v1 = __expf(us2f((unsigned short)(u >> 16))) * rd;
                pg32[(size_t)(b * NPOS + n0 + n) * 64 + c2] =
                    (unsigned)f2us(v0) | ((unsigned)f2us(v1) << 16);
            }
        }
    }
}

// ---------------------------------------------------------------------------
// K2: unnormalized context + sumexp partials (dense kvt [b][n][256] input).
// ctxu[(bh,sp)][d][e] = sum_n exp(k[n,d]) * v[n,e]; separt = sum exp.
// ---------------------------------------------------------------------------
__global__ __launch_bounds__(256)
void context_kernel(const bf16* __restrict__ kvt, float* __restrict__ ctxu,
                    float* __restrict__ separt) {
    __shared__ float ks[128][36];
    __shared__ float vs[128][36];
    __shared__ float red_se[4][32];
    int sp = blockIdx.x, h = blockIdx.y, b = blockIdx.z;
    int tid = threadIdx.x;
    int wave = tid >> 6, lane = tid & 63;
    int eg = lane & 7, dg = lane >> 3;
    int sd = tid & 31, sq = (tid >> 5) & 3;
    const int koff = h * DH, voff = 128 + h * DH;
    size_t rowbase = ((size_t)b * NPOS + sp * 1024) * 256;

    float acc[4][4] = {};
    float se_loc = 0.f;

    for (int nc = 0; nc < 1024; nc += 128) {
        for (int t = tid; t < 1024; t += 256) {
            int n = t >> 3, dq = t & 7;
            const bf16* row = kvt + rowbase + (size_t)(nc + n) * 256;
            ushort4 ku = *(const ushort4*)(row + koff + dq * 4);
            ushort4 vu = *(const ushort4*)(row + voff + dq * 4);
            f32x4 kf, vf;
            kf[0] = __expf(us2f(ku.x)); kf[1] = __expf(us2f(ku.y));
            kf[2] = __expf(us2f(ku.z)); kf[3] = __expf(us2f(ku.w));
            vf[0] = us2f(vu.x); vf[1] = us2f(vu.y); vf[2] = us2f(vu.z); vf[3] = us2f(vu.w);
            *(f32x4*)&ks[n][dq * 4] = kf;
            *(f32x4*)&vs[n][dq * 4] = vf;
        }
        __syncthreads();
        #pragma unroll 4
        for (int i = 0; i < 32; ++i) {
            int n = wave * 32 + i;
            f32x4 kv = *(const f32x4*)&ks[n][dg * 4];
            f32x4 vv = *(const f32x4*)&vs[n][eg * 4];
            #pragma unroll
            for (int j = 0; j < 4; ++j)
                #pragma unroll
                for (int i2 = 0; i2 < 4; ++i2)
                    acc[j][i2] += kv[j] * vv[i2];
        }
        if (tid < 128) {
            float s = 0.f;
            #pragma unroll 8
            for (int i = 0; i < 32; ++i) s += ks[sq * 32 + i][sd];
            se_loc += s;
        }
        __syncthreads();
    }

    if (tid < 128) red_se[sq][sd] = se_loc;
    float* red = &ks[0][0];   // 4608 floats >= 4096
    #pragma unroll
    for (int j = 0; j < 4; ++j)
        #pragma unroll
        for (int i = 0; i < 4; ++i)
            red[(wave * 64 + lane) * 16 + j * 4 + i] = acc[j][i];
    __syncthreads();
    size_t bhsp = ((size_t)(b * HEADS + h) * 4 + sp);
    for (int idx = tid; idx < 1024; idx += 256) {
        int d = idx >> 5, e = idx & 31;
        int l = (d >> 2) * 8 + (e >> 2);
        int slot = (d & 3) * 4 + (e & 3);
        float s = 0.f;
        #pragma unroll
        for (int w = 0; w < 4; ++w) s += red[(w * 64 + l) * 16 + slot];
        ctxu[bhsp * 1024 + idx] = s;
    }
    if (tid < 32) {
        float s = red_se[0][tid] + red_se[1][tid] + red_se[2][tid] + red_se[3][tid];
        separt[bhsp * 32 + tid] = s;
    }
}

// ---------------------------------------------------------------------------
// K3: wmod_b[c][h*32+d] = (sum_e Wout[c][h*32+e]*ctx[h][d][e]) / se[h,d] / (N*sqrt32)
// ---------------------------------------------------------------------------
__global__ __launch_bounds__(256)
void wmod_kernel(const float* __restrict__ Wout, const float* __restrict__ ctxu,
                 const float* __restrict__ separt, bf16* __restrict__ wmod) {
    __shared__ float cs[4096];
    __shared__ float ses[128];
    int cg = blockIdx.x, b = blockIdx.y;
    int tid = threadIdx.x;
    for (int idx = tid; idx < 4096; idx += 256) {
        int hh = idx >> 10, rest = idx & 1023;
        float s = 0.f;
        #pragma unroll
        for (int sp = 0; sp < 4; ++sp)
            s += ctxu[(((size_t)(b * HEADS + hh) * 4) + sp) * 1024 + rest];
        cs[idx] = s;
    }
    if (tid < 128) {
        int hh = tid >> 5, d = tid & 31;
        float s = 0.f;
        #pragma unroll
        for (int sp = 0; sp < 4; ++sp)
            s += separt[(((size_t)(b * HEADS + hh) * 4) + sp) * 32 + d];
        ses[tid] = s;
    }
    __syncthreads();
    int c = cg * 32 + (tid & 31);
    int g = tid >> 5;
    int h = g >> 1, d0 = (g & 1) * 16;
    const float* wr = Wout + (size_t)c * INNER + h * DH;
    float w[32];
    #pragma unroll
    for (int i = 0; i < 8; ++i) {
        float4 t = *(const float4*)&wr[i * 4];
        w[i * 4] = t.x; w[i * 4 + 1] = t.y; w[i * 4 + 2] = t.z; w[i * 4 + 3] = t.w;
    }
    const float SCALE = 4.3158341e-05f;   // 1/(4096*sqrt(32))
    #pragma unroll
    for (int dd = 0; dd < 16; ++dd) {
        int d = d0 + dd;
        const float* cr = &cs[h * 1024 + d * 32];
        float s = 0.f;
        #pragma unroll
        for (int e4 = 0; e4 < 8; ++e4) {
            f32x4 t = *(const f32x4*)&cr[e4 * 4];
            s += w[e4 * 4] * t[0] + w[e4 * 4 + 1] * t[1]
               + w[e4 * 4 + 2] * t[2] + w[e4 * 4 + 3] * t[3];
        }
        float val = s * SCALE / ses[h * 32 + d];
        wmod[((size_t)b * CH + c) * INNER + h * DH + d] = f2b(val);
    }
}

// ---------------------------------------------------------------------------
// K4: fused y-GEMM (y[n][c] = sum_hd p[n][hd]*wmod[c][hd] + bout[c]) + channel
// LN + residual -> out fp32. grid (32 n-tiles, 16 b). One block = 128n x 256c.
// B-fragments (wmod, 64 KB/batch, L2-resident) read directly from global:
// no Bw staging, barrier-free k-loop, LDS 51.2 KB -> 37.9 KB.
// ---------------------------------------------------------------------------
__global__ __launch_bounds__(256)
void fused_out_kernel(const bf16* __restrict__ p, const bf16* __restrict__ wmod,
                      const float* __restrict__ bout, const float* __restrict__ x,
                      float* __restrict__ out) {
    __shared__ char lds[37888];
    bf16* Ap = (bf16*)lds;                 // [128][136] = 34816 B (union: ct)
    float* ct = (float*)lds;               // [256][33] f32 = 33792 B
    float* st = (float*)(lds + 34816);     // stats: [2][128][2] + musr[128][2] = 3072 B

    const int b = blockIdx.y, n0 = blockIdx.x * 128;
    const int tid = threadIdx.x;
    const int wave = tid >> 6, lane = tid & 63;
    const int wm = (wave >> 1) * 64, wn2 = (wave & 1) * 128;
    const int lrow = lane & 15, kq = lane >> 4;

    // stage Ap = p tile [128][128]
    {
        const unsigned* pg32 = (const unsigned*)p;
        unsigned* A32 = (unsigned*)Ap;
        #pragma unroll 4
        for (int i = 0; i < 32; ++i) {
            int idx = i * 256 + tid;
            int c2 = idx & 63, n = idx >> 6;
            A32[n * 68 + c2] = pg32[(size_t)(b * NPOS + n0 + n) * 64 + c2];
        }
    }
    __syncthreads();

    f32x4 acc[4][8];
    #pragma unroll
    for (int i = 0; i < 4; ++i)
        #pragma unroll
        for (int j = 0; j < 8; ++j) acc[i][j] = (f32x4){0.f, 0.f, 0.f, 0.f};

    const bf16* wb = wmod + (size_t)b * CH * INNER;
    #pragma unroll 2
    for (int k0 = 0; k0 < 128; k0 += 32) {
        bf8v af[4], bfr[8];
        #pragma unroll
        for (int t = 0; t < 4; ++t)
            af[t] = *(const bf8v*)&Ap[(wm + t * 16 + lrow) * 136 + k0 + kq * 8];
        #pragma unroll
        for (int t = 0; t < 8; ++t)
            bfr[t] = *(const bf8v*)&wb[(size_t)(wn2 + t * 16 + lrow) * 128 + k0 + kq * 8];
        #pragma unroll
        for (int mt = 0; mt < 4; ++mt)
            #pragma unroll
            for (int nt = 0; nt < 8; ++nt)
                acc[mt][nt] = __builtin_amdgcn_mfma_f32_16x16x32_bf16(
                    af[mt], bfr[nt], acc[mt][nt], 0, 0, 0);
    }

    // bias add (before LN, matches reference)
    #pragma unroll
    for (int nt = 0; nt < 8; ++nt) {
        float bv = bout[wn2 + nt * 16 + lrow];
        #pragma unroll
        for (int mt = 0; mt < 4; ++mt)
            #pragma unroll
            for (int r = 0; r < 4; ++r) acc[mt][nt][r] += bv;
    }

    // LN stats: per (mt,r) row, sum over this wave's 128 cols via shfl_xor on lrow
    // (st region is disjoint from Ap -> no barrier needed before the writes)
    #pragma unroll
    for (int mt = 0; mt < 4; ++mt)
        #pragma unroll
        for (int r = 0; r < 4; ++r) {
            float s = 0.f, sq = 0.f;
            #pragma unroll
            for (int nt = 0; nt < 8; ++nt) {
                float v = acc[mt][nt][r];
                s += v; sq += v * v;
            }
            #pragma unroll
            for (int m = 1; m <= 8; m <<= 1) {
                s += __shfl_xor(s, m, 64);
                sq += __shfl_xor(sq, m, 64);
            }
            if (lrow == 0) {
                int row = wm + mt * 16 + kq * 4 + r;
                st[(wave & 1) * 256 + row * 2] = s;
                st[(wave & 1) * 256 + row * 2 + 1] = sq;
            }
        }
    __syncthreads();
    if (tid < 128) {
        float s  = st[tid * 2] + st[256 + tid * 2];
        float sq = st[tid * 2 + 1] + st[256 + tid * 2 + 1];
        float m = s * (1.f / 256.f);
        float var = sq * (1.f / 256.f) - m * m;
        st[512 + tid * 2] = m;
        st[512 + tid * 2 + 1] = rsqrtf(var + 1e-5f);
    }
    __syncthreads();
    // normalize accs in place
    #pragma unroll
    for (int mt = 0; mt < 4; ++mt)
        #pragma unroll
        for (int r = 0; r < 4; ++r) {
            int row = wm + mt * 16 + kq * 4 + r;
            float m = st[512 + row * 2], rs = st[512 + row * 2 + 1];
            #pragma unroll
            for (int nt = 0; nt < 8; ++nt)
                acc[mt][nt][r] = (acc[mt][nt][r] - m) * rs;
        }

    // 4 output chunks of 32 rows: LDS transpose -> coalesced fp32 store + residual
    for (int pr = 0; pr < 4; ++pr) {
        __syncthreads();
        if ((wave >> 1) == (pr >> 1)) {
            int mtb = (pr & 1) * 2;
            #pragma unroll
            for (int mi = 0; mi < 2; ++mi) {
                int mt = mtb + mi;
                #pragma unroll
                for (int nt = 0; nt < 8; ++nt)
                    #pragma unroll
                    for (int r = 0; r < 4; ++r) {
                        int rl = mi * 16 + kq * 4 + r;
                        ct[(wn2 + nt * 16 + lrow) * 33 + rl] = acc[mt][nt][r];
                    }
            }
        }
        __syncthreads();
        #pragma unroll 4
        for (int i = 0; i < 32; ++i) {
            int idx = i * 256 + tid;       // 8192 f32
            int n = idx & 31, c = idx >> 5;
            size_t gi = ((size_t)b * CH + c) * NPOS + n0 + pr * 32 + n;
            out[gi] = ct[c * 33 + n] + x[gi];
        }
    }
}

// ---------------------------------------------------------------------------
extern "C" void kernel_launch(void* const* d_in, const int* in_sizes, int n_in,
                              void* d_out, int out_size, void* d_ws, size_t ws_size,
                              hipStream_t stream) {
    const float* x    = (const float*)d_in[0];   // [16,256,64,64]
    const float* Wqkv = (const float*)d_in[1];   // [384,256]
    const float* Wout = (const float*)d_in[2];   // [256,128]
    const float* bout = (const float*)d_in[3];   // [256]
    float* out = (float*)d_out;

    // workspace (~52.5 MB, unchanged footprint)
    char* ws = (char*)d_ws;
    bf16*  p      = (bf16*)ws;                       // 16*4096*128*2 = 16777216
    bf16*  kvt    = (bf16*)(ws + 16777216);          // 16*4096*256*2 = 33554432
    float* ctxu   = (float*)(ws + 50331648);         // 16*4*4*1024*4 = 1048576
    float* separt = (float*)(ws + 51380224);         // 32768
    bf16*  wmod   = (bf16*)(ws + 51412992);          // 16*256*128*2 = 1048576
    // wqb overlays the ctxu region (192 KB): dead before K2 writes ctxu.
    bf16*  wqb    = (bf16*)(ws + 50331648);          // 384*256*2 = 196608

    prep_w_kernel<<<dim3(96), 256, 0, stream>>>(Wqkv, wqb);
    fused_qkv_kernel<<<dim3(32, BATCH), 256, 0, stream>>>(x, wqb, p, kvt);
    context_kernel<<<dim3(4, HEADS, BATCH), 256, 0, stream>>>(kvt, ctxu, separt);
    wmod_kernel<<<dim3(8, BATCH), 256, 0, stream>>>(Wout, ctxu, separt, wmod);
    fused_out_kernel<<<dim3(32, BATCH), 256, 0, stream>>>(p, wmod, bout, x, out);
}

// Round 2
// 211.551 us; speedup vs baseline: 1.1047x; 1.1047x over previous
//
#include <hip/hip_runtime.h>
#include <hip/hip_bf16.h>
#include <math.h>

// AttnBlock: B=16, C=256, H=W=64, heads=4, dim_head=32
#define BATCH 16
#define CH 256
#define NPOS 4096
#define INNER 128
#define HEADS 4
#define DH 32

typedef __hip_bfloat16 bf16;
typedef short bf8v __attribute__((ext_vector_type(8)));    // 8 bf16 (4 VGPRs)
typedef float f32x4 __attribute__((ext_vector_type(4)));

__device__ __forceinline__ float b2f(bf16 v) { return __bfloat162float(v); }
__device__ __forceinline__ float us2f(unsigned short u) {
    unsigned w = ((unsigned)u) << 16; float f; __builtin_memcpy(&f, &w, 4); return f;
}
__device__ __forceinline__ unsigned short f2us(float f) {
    bf16 h = __float2bfloat16(f); unsigned short u; __builtin_memcpy(&u, &h, 2); return u;
}
__device__ __forceinline__ bf16 f2b(float v) { return __float2bfloat16(v); }

// ---------------------------------------------------------------------------
// K0: one-shot Wqkv fp32 -> bf16 (same rounding as original per-block staging).
// ---------------------------------------------------------------------------
__global__ __launch_bounds__(256)
void prep_w_kernel(const float* __restrict__ Wqkv, bf16* __restrict__ wqb) {
    int idx = (blockIdx.x * 256 + threadIdx.x) * 4;
    float4 w = *(const float4*)&Wqkv[idx];
    ushort4 u;
    u.x = f2us(w.x); u.y = f2us(w.y); u.z = f2us(w.z); u.w = f2us(w.w);
    *(ushort4*)&wqb[idx] = u;
}

// ---------------------------------------------------------------------------
// K1: fused LN + qkv GEMM + q-softmax. 64-row n-tiles for occupancy:
// LDS = A[64][264] bf16 + stats = 35.8 KB -> 4 blocks/CU; acc 4x2 -> ~110 VGPR
// -> 4 waves/SIMD. B-frags direct from L2 (wqb); k/v stored scattered (no
// transpose epilogue); q-softmax fully in-register (head == wave, DH=32).
// 3 barriers total, all in the LN prologue.
// ---------------------------------------------------------------------------
__global__ __launch_bounds__(256)
void fused_qkv_kernel(const float* __restrict__ x, const bf16* __restrict__ wqb,
                      bf16* __restrict__ p, bf16* __restrict__ kvt) {
    __shared__ bf16 A[64 * 264];       // 33792 B
    __shared__ float stats[512];       // 2048 B

    const int b = blockIdx.y, n0 = blockIdx.x * 64;
    const int tid = threadIdx.x;
    const int w = tid >> 6, lane = tid & 63;
    const int lrow = lane & 15, kq = lane >> 4;

    // ---- stage x tile (raw bf16) + per-thread LN partial stats ----
    {
        const int n = tid & 63, cq = tid >> 6;
        const float* xp = x + ((size_t)b * CH + cq * 64) * NPOS + n0 + n;
        float s = 0.f, sq = 0.f;
        for (int i0 = 0; i0 < 64; i0 += 8) {
            bf8v bv;
            #pragma unroll
            for (int j = 0; j < 8; ++j) {
                float v = xp[(size_t)(i0 + j) * NPOS];
                s += v; sq += v * v;
                bv[j] = (short)f2us(v);
            }
            *(bf8v*)&A[n * 264 + cq * 64 + i0] = bv;
        }
        stats[tid * 2] = s; stats[tid * 2 + 1] = sq;
    }
    __syncthreads();
    if (tid < 64) {
        float s  = stats[tid * 2]     + stats[(tid + 64) * 2]
                 + stats[(tid + 128) * 2] + stats[(tid + 192) * 2];
        float sq = stats[tid * 2 + 1] + stats[(tid + 64) * 2 + 1]
                 + stats[(tid + 128) * 2 + 1] + stats[(tid + 192) * 2 + 1];
        float m = s * (1.f / 256.f);
        float var = sq * (1.f / 256.f) - m * m;
        stats[tid * 2] = m;
        stats[tid * 2 + 1] = rsqrtf(var + 1e-5f);
    }
    __syncthreads();
    // ---- normalize A in place (u32 pairs, c-fast) ----
    {
        unsigned* A32 = (unsigned*)A;
        #pragma unroll 4
        for (int i = 0; i < 32; ++i) {
            int idx = i * 256 + tid;
            int c2 = idx & 127, n = idx >> 7;
            unsigned u = A32[n * 132 + c2];
            float m = stats[n * 2], rs = stats[n * 2 + 1];
            float v0 = (us2f((unsigned short)(u & 0xffffu)) - m) * rs;
            float v1 = (us2f((unsigned short)(u >> 16)) - m) * rs;
            A32[n * 132 + c2] = (unsigned)f2us(v0) | ((unsigned)f2us(v1) << 16);
        }
    }
    __syncthreads();   // A normalized; read-only for the rest of the kernel

    for (int ph = 0; ph < 3; ++ph) {
        const int colbase = (ph == 2) ? 0 : (ph + 1) * 128;   // k, v, q
        const bf16* wp = wqb + (size_t)(colbase + w * 32) * 256;
        f32x4 acc[4][2];
        #pragma unroll
        for (int i = 0; i < 4; ++i) {
            acc[i][0] = (f32x4){0.f, 0.f, 0.f, 0.f};
            acc[i][1] = (f32x4){0.f, 0.f, 0.f, 0.f};
        }

        // barrier-free k-loop: A frags from LDS, B frags straight from L2
        #pragma unroll 2
        for (int k0 = 0; k0 < 256; k0 += 32) {
            bf8v af[4], bfr[2];
            #pragma unroll
            for (int t = 0; t < 4; ++t)
                af[t] = *(const bf8v*)&A[(t * 16 + lrow) * 264 + k0 + kq * 8];
            #pragma unroll
            for (int t = 0; t < 2; ++t)
                bfr[t] = *(const bf8v*)&wp[(size_t)(t * 16 + lrow) * 256 + k0 + kq * 8];
            #pragma unroll
            for (int mt = 0; mt < 4; ++mt)
                #pragma unroll
                for (int nt = 0; nt < 2; ++nt)
                    acc[mt][nt] = __builtin_amdgcn_mfma_f32_16x16x32_bf16(
                        af[mt], bfr[nt], acc[mt][nt], 0, 0, 0);
        }

        if (ph < 2) {
            // direct scattered bf16 stores (quarter-wave 32B segments, L2 merges)
            #pragma unroll
            for (int mt = 0; mt < 4; ++mt)
                #pragma unroll
                for (int nt = 0; nt < 2; ++nt)
                    #pragma unroll
                    for (int r = 0; r < 4; ++r) {
                        int row = mt * 16 + kq * 4 + r;
                        int col = w * 32 + nt * 16 + lrow;
                        kvt[(size_t)(b * NPOS + n0 + row) * 256 + ph * 128 + col] =
                            f2b(acc[mt][nt][r]);
                    }
        } else {
            // q epilogue fully in-register: wave w == head w (DH==32).
            // For each (mt,r): row = mt*16+kq*4+r; 32 cols live in 16 lanes x 2 regs.
            #pragma unroll
            for (int mt = 0; mt < 4; ++mt)
                #pragma unroll
                for (int r = 0; r < 4; ++r) {
                    // bf16-round before exp to match original numerics; no max-sub
                    float e0 = __expf(b2f(f2b(acc[mt][0][r])));
                    float e1 = __expf(b2f(f2b(acc[mt][1][r])));
                    float s = e0 + e1;
                    #pragma unroll
                    for (int m = 1; m <= 8; m <<= 1) s += __shfl_xor(s, m, 64);
                    float rd = 1.f / s;
                    int row = mt * 16 + kq * 4 + r;
                    bf16* pr_ = p + (size_t)(b * NPOS + n0 + row) * 128 + w * 32 + lrow;
                    pr_[0]  = f2b(e0 * rd);
                    pr_[16] = f2b(e1 * rd);
                }
        }
    }
}

// ---------------------------------------------------------------------------
// K2: unnormalized context + sumexp partials (dense kvt [b][n][256] input).
// ctxu[(bh,sp)][d][e] = sum_n exp(k[n,d]) * v[n,e]; separt = sum exp.
// ---------------------------------------------------------------------------
__global__ __launch_bounds__(256)
void context_kernel(const bf16* __restrict__ kvt, float* __restrict__ ctxu,
                    float* __restrict__ separt) {
    __shared__ float ks[128][36];
    __shared__ float vs[128][36];
    __shared__ float red_se[4][32];
    int sp = blockIdx.x, h = blockIdx.y, b = blockIdx.z;
    int tid = threadIdx.x;
    int wave = tid >> 6, lane = tid & 63;
    int eg = lane & 7, dg = lane >> 3;
    int sd = tid & 31, sq = (tid >> 5) & 3;
    const int koff = h * DH, voff = 128 + h * DH;
    size_t rowbase = ((size_t)b * NPOS + sp * 1024) * 256;

    float acc[4][4] = {};
    float se_loc = 0.f;

    for (int nc = 0; nc < 1024; nc += 128) {
        for (int t = tid; t < 1024; t += 256) {
            int n = t >> 3, dq = t & 7;
            const bf16* row = kvt + rowbase + (size_t)(nc + n) * 256;
            ushort4 ku = *(const ushort4*)(row + koff + dq * 4);
            ushort4 vu = *(const ushort4*)(row + voff + dq * 4);
            f32x4 kf, vf;
            kf[0] = __expf(us2f(ku.x)); kf[1] = __expf(us2f(ku.y));
            kf[2] = __expf(us2f(ku.z)); kf[3] = __expf(us2f(ku.w));
            vf[0] = us2f(vu.x); vf[1] = us2f(vu.y); vf[2] = us2f(vu.z); vf[3] = us2f(vu.w);
            *(f32x4*)&ks[n][dq * 4] = kf;
            *(f32x4*)&vs[n][dq * 4] = vf;
        }
        __syncthreads();
        #pragma unroll 4
        for (int i = 0; i < 32; ++i) {
            int n = wave * 32 + i;
            f32x4 kv = *(const f32x4*)&ks[n][dg * 4];
            f32x4 vv = *(const f32x4*)&vs[n][eg * 4];
            #pragma unroll
            for (int j = 0; j < 4; ++j)
                #pragma unroll
                for (int i2 = 0; i2 < 4; ++i2)
                    acc[j][i2] += kv[j] * vv[i2];
        }
        if (tid < 128) {
            float s = 0.f;
            #pragma unroll 8
            for (int i = 0; i < 32; ++i) s += ks[sq * 32 + i][sd];
            se_loc += s;
        }
        __syncthreads();
    }

    if (tid < 128) red_se[sq][sd] = se_loc;
    float* red = &ks[0][0];   // 4608 floats >= 4096
    #pragma unroll
    for (int j = 0; j < 4; ++j)
        #pragma unroll
        for (int i = 0; i < 4; ++i)
            red[(wave * 64 + lane) * 16 + j * 4 + i] = acc[j][i];
    __syncthreads();
    size_t bhsp = ((size_t)(b * HEADS + h) * 4 + sp);
    for (int idx = tid; idx < 1024; idx += 256) {
        int d = idx >> 5, e = idx & 31;
        int l = (d >> 2) * 8 + (e >> 2);
        int slot = (d & 3) * 4 + (e & 3);
        float s = 0.f;
        #pragma unroll
        for (int w = 0; w < 4; ++w) s += red[(w * 64 + l) * 16 + slot];
        ctxu[bhsp * 1024 + idx] = s;
    }
    if (tid < 32) {
        float s = red_se[0][tid] + red_se[1][tid] + red_se[2][tid] + red_se[3][tid];
        separt[bhsp * 32 + tid] = s;
    }
}

// ---------------------------------------------------------------------------
// K3: wmod_b[c][h*32+d] = (sum_e Wout[c][h*32+e]*ctx[h][d][e]) / se[h,d] / (N*sqrt32)
// ---------------------------------------------------------------------------
__global__ __launch_bounds__(256)
void wmod_kernel(const float* __restrict__ Wout, const float* __restrict__ ctxu,
                 const float* __restrict__ separt, bf16* __restrict__ wmod) {
    __shared__ float cs[4096];
    __shared__ float ses[128];
    int cg = blockIdx.x, b = blockIdx.y;
    int tid = threadIdx.x;
    for (int idx = tid; idx < 4096; idx += 256) {
        int hh = idx >> 10, rest = idx & 1023;
        float s = 0.f;
        #pragma unroll
        for (int sp = 0; sp < 4; ++sp)
            s += ctxu[(((size_t)(b * HEADS + hh) * 4) + sp) * 1024 + rest];
        cs[idx] = s;
    }
    if (tid < 128) {
        int hh = tid >> 5, d = tid & 31;
        float s = 0.f;
        #pragma unroll
        for (int sp = 0; sp < 4; ++sp)
            s += separt[(((size_t)(b * HEADS + hh) * 4) + sp) * 32 + d];
        ses[tid] = s;
    }
    __syncthreads();
    int c = cg * 32 + (tid & 31);
    int g = tid >> 5;
    int h = g >> 1, d0 = (g & 1) * 16;
    const float* wr = Wout + (size_t)c * INNER + h * DH;
    float w[32];
    #pragma unroll
    for (int i = 0; i < 8; ++i) {
        float4 t = *(const float4*)&wr[i * 4];
        w[i * 4] = t.x; w[i * 4 + 1] = t.y; w[i * 4 + 2] = t.z; w[i * 4 + 3] = t.w;
    }
    const float SCALE = 4.3158341e-05f;   // 1/(4096*sqrt(32))
    #pragma unroll
    for (int dd = 0; dd < 16; ++dd) {
        int d = d0 + dd;
        const float* cr = &cs[h * 1024 + d * 32];
        float s = 0.f;
        #pragma unroll
        for (int e4 = 0; e4 < 8; ++e4) {
            f32x4 t = *(const f32x4*)&cr[e4 * 4];
            s += w[e4 * 4] * t[0] + w[e4 * 4 + 1] * t[1]
               + w[e4 * 4 + 2] * t[2] + w[e4 * 4 + 3] * t[3];
        }
        float val = s * SCALE / ses[h * 32 + d];
        wmod[((size_t)b * CH + c) * INNER + h * DH + d] = f2b(val);
    }
}

// ---------------------------------------------------------------------------
// K4: fused y-GEMM + bias + channel LN + residual. 64-row n-tiles:
// LDS = max(Ap 17.4KB, ct 33.8KB) + st 2.6KB = 36.4 KB -> 4 blocks/CU;
// acc 4x4 (64 VGPR) -> 4 waves/SIMD. wmod B-frags direct from L2.
// ---------------------------------------------------------------------------
__global__ __launch_bounds__(256)
void fused_out_kernel(const bf16* __restrict__ p, const bf16* __restrict__ wmod,
                      const float* __restrict__ bout, const float* __restrict__ x,
                      float* __restrict__ out) {
    __shared__ char lds[36864];
    bf16* Ap = (bf16*)lds;                 // [64][136] = 17408 B (union: ct)
    float* ct = (float*)lds;               // [256][33] f32 = 33792 B
    float* st = (float*)(lds + 33792);     // [4][64][2] partials + [64][2] musr

    const int b = blockIdx.y, n0 = blockIdx.x * 64;
    const int tid = threadIdx.x;
    const int w = tid >> 6, lane = tid & 63;
    const int lrow = lane & 15, kq = lane >> 4;

    // stage Ap = p tile [64][128]
    {
        const unsigned* pg32 = (const unsigned*)p;
        unsigned* A32 = (unsigned*)Ap;
        #pragma unroll 4
        for (int i = 0; i < 16; ++i) {
            int idx = i * 256 + tid;
            int c2 = idx & 63, n = idx >> 6;
            A32[n * 68 + c2] = pg32[(size_t)(b * NPOS + n0 + n) * 64 + c2];
        }
    }
    __syncthreads();

    f32x4 acc[4][4];
    #pragma unroll
    for (int i = 0; i < 4; ++i)
        #pragma unroll
        for (int j = 0; j < 4; ++j) acc[i][j] = (f32x4){0.f, 0.f, 0.f, 0.f};

    const bf16* wb = wmod + (size_t)b * CH * INNER + (size_t)(w * 64) * INNER;
    #pragma unroll 2
    for (int k0 = 0; k0 < 128; k0 += 32) {
        bf8v af[4], bfr[4];
        #pragma unroll
        for (int t = 0; t < 4; ++t)
            af[t] = *(const bf8v*)&Ap[(t * 16 + lrow) * 136 + k0 + kq * 8];
        #pragma unroll
        for (int t = 0; t < 4; ++t)
            bfr[t] = *(const bf8v*)&wb[(size_t)(t * 16 + lrow) * 128 + k0 + kq * 8];
        #pragma unroll
        for (int mt = 0; mt < 4; ++mt)
            #pragma unroll
            for (int nt = 0; nt < 4; ++nt)
                acc[mt][nt] = __builtin_amdgcn_mfma_f32_16x16x32_bf16(
                    af[mt], bfr[nt], acc[mt][nt], 0, 0, 0);
    }

    // bias add (before LN, matches reference)
    #pragma unroll
    for (int nt = 0; nt < 4; ++nt) {
        float bv = bout[w * 64 + nt * 16 + lrow];
        #pragma unroll
        for (int mt = 0; mt < 4; ++mt)
            #pragma unroll
            for (int r = 0; r < 4; ++r) acc[mt][nt][r] += bv;
    }

    // LN stats: per (mt,r) row, sum over this wave's 64 cols via shfl on lrow
    #pragma unroll
    for (int mt = 0; mt < 4; ++mt)
        #pragma unroll
        for (int r = 0; r < 4; ++r) {
            float s = 0.f, sq = 0.f;
            #pragma unroll
            for (int nt = 0; nt < 4; ++nt) {
                float v = acc[mt][nt][r];
                s += v; sq += v * v;
            }
            #pragma unroll
            for (int m = 1; m <= 8; m <<= 1) {
                s += __shfl_xor(s, m, 64);
                sq += __shfl_xor(sq, m, 64);
            }
            if (lrow == 0) {
                int row = mt * 16 + kq * 4 + r;
                st[w * 128 + row * 2] = s;
                st[w * 128 + row * 2 + 1] = sq;
            }
        }
    __syncthreads();
    if (tid < 64) {
        float s  = st[tid * 2]     + st[128 + tid * 2]
                 + st[256 + tid * 2] + st[384 + tid * 2];
        float sq = st[tid * 2 + 1] + st[128 + tid * 2 + 1]
                 + st[256 + tid * 2 + 1] + st[384 + tid * 2 + 1];
        float m = s * (1.f / 256.f);
        float var = sq * (1.f / 256.f) - m * m;
        st[512 + tid * 2] = m;
        st[512 + tid * 2 + 1] = rsqrtf(var + 1e-5f);
    }
    __syncthreads();
    // normalize accs in place
    #pragma unroll
    for (int mt = 0; mt < 4; ++mt)
        #pragma unroll
        for (int r = 0; r < 4; ++r) {
            int row = mt * 16 + kq * 4 + r;
            float m = st[512 + row * 2], rs = st[512 + row * 2 + 1];
            #pragma unroll
            for (int nt = 0; nt < 4; ++nt)
                acc[mt][nt][r] = (acc[mt][nt][r] - m) * rs;
        }

    // 2 output chunks of 32 rows: LDS transpose -> coalesced fp32 store + residual
    for (int pr = 0; pr < 2; ++pr) {
        __syncthreads();
        #pragma unroll
        for (int mi = 0; mi < 2; ++mi) {
            int mt = pr * 2 + mi;
            #pragma unroll
            for (int nt = 0; nt < 4; ++nt)
                #pragma unroll
                for (int r = 0; r < 4; ++r) {
                    int rl = mi * 16 + kq * 4 + r;
                    ct[(w * 64 + nt * 16 + lrow) * 33 + rl] = acc[mt][nt][r];
                }
        }
        __syncthreads();
        #pragma unroll 4
        for (int i = 0; i < 32; ++i) {
            int idx = i * 256 + tid;       // 8192 f32
            int n = idx & 31, c = idx >> 5;
            size_t gi = ((size_t)b * CH + c) * NPOS + n0 + pr * 32 + n;
            out[gi] = ct[c * 33 + n] + x[gi];
        }
    }
}

// ---------------------------------------------------------------------------
extern "C" void kernel_launch(void* const* d_in, const int* in_sizes, int n_in,
                              void* d_out, int out_size, void* d_ws, size_t ws_size,
                              hipStream_t stream) {
    const float* x    = (const float*)d_in[0];   // [16,256,64,64]
    const float* Wqkv = (const float*)d_in[1];   // [384,256]
    const float* Wout = (const float*)d_in[2];   // [256,128]
    const float* bout = (const float*)d_in[3];   // [256]
    float* out = (float*)d_out;

    // workspace (~52.5 MB, unchanged footprint)
    char* ws = (char*)d_ws;
    bf16*  p      = (bf16*)ws;                       // 16*4096*128*2 = 16777216
    bf16*  kvt    = (bf16*)(ws + 16777216);          // 16*4096*256*2 = 33554432
    float* ctxu   = (float*)(ws + 50331648);         // 16*4*4*1024*4 = 1048576
    float* separt = (float*)(ws + 51380224);         // 32768
    bf16*  wmod   = (bf16*)(ws + 51412992);          // 16*256*128*2 = 1048576
    // wqb overlays the ctxu region (192 KB): dead before K2 writes ctxu.
    bf16*  wqb    = (bf16*)(ws + 50331648);          // 384*256*2 = 196608

    prep_w_kernel<<<dim3(96), 256, 0, stream>>>(Wqkv, wqb);
    fused_qkv_kernel<<<dim3(64, BATCH), 256, 0, stream>>>(x, wqb, p, kvt);
    context_kernel<<<dim3(4, HEADS, BATCH), 256, 0, stream>>>(kvt, ctxu, separt);
    wmod_kernel<<<dim3(8, BATCH), 256, 0, stream>>>(Wout, ctxu, separt, wmod);
    fused_out_kernel<<<dim3(64, BATCH), 256, 0, stream>>>(p, wmod, bout, x, out);
}

// Round 3
// 194.050 us; speedup vs baseline: 1.2044x; 1.0902x over previous
//
#include <hip/hip_runtime.h>
#include <hip/hip_bf16.h>
#include <math.h>

// AttnBlock: B=16, C=256, H=W=64, heads=4, dim_head=32
#define BATCH 16
#define CH 256
#define NPOS 4096
#define INNER 128
#define HEADS 4
#define DH 32

typedef __hip_bfloat16 bf16;
typedef short bf8v __attribute__((ext_vector_type(8)));    // 8 bf16 (4 VGPRs)
typedef float f32x4 __attribute__((ext_vector_type(4)));

__device__ __forceinline__ float b2f(bf16 v) { return __bfloat162float(v); }
__device__ __forceinline__ float us2f(unsigned short u) {
    unsigned w = ((unsigned)u) << 16; float f; __builtin_memcpy(&f, &w, 4); return f;
}
__device__ __forceinline__ unsigned short f2us(float f) {
    bf16 h = __float2bfloat16(f); unsigned short u; __builtin_memcpy(&u, &h, 2); return u;
}
__device__ __forceinline__ bf16 f2b(float v) { return __float2bfloat16(v); }

// ---------------------------------------------------------------------------
// K0: one-shot Wqkv fp32 -> bf16 (same rounding as original per-block staging).
// ---------------------------------------------------------------------------
__global__ __launch_bounds__(256)
void prep_w_kernel(const float* __restrict__ Wqkv, bf16* __restrict__ wqb) {
    int idx = (blockIdx.x * 256 + threadIdx.x) * 4;
    float4 w = *(const float4*)&Wqkv[idx];
    ushort4 u;
    u.x = f2us(w.x); u.y = f2us(w.y); u.z = f2us(w.z); u.w = f2us(w.w);
    *(ushort4*)&wqb[idx] = u;
}

// ---------------------------------------------------------------------------
// K1: fused LN + qkv GEMM + q-softmax + PER-TILE CONTEXT PARTIALS.
// kvt is never materialized: after the k and v phases, each wave (== head)
// computes ctx_partial[32d][32e] = sum_n exp(k[n,d]) * v[n,e] over its 64-n
// tile with one 2x2x(K=64) MFMA pass through a per-wave LDS transpose tile,
// plus sumexp partials. Partials go to ctxp (17.3 MB, L3-resident).
// x staged with float4 loads (4x bytes-in-flight vs scalar).
// p stored as packed u32 with head-dim permutation pi(d)=(d&15)*2+(d>>4)
// (wmod store in K3 permuted identically -> dot products invariant).
// ---------------------------------------------------------------------------
__global__ __launch_bounds__(256)
void fused_qkv_kernel(const float* __restrict__ x, const bf16* __restrict__ wqb,
                      bf16* __restrict__ p, float* __restrict__ ctxp) {
    __shared__ char smem[36864];       // A[64][264] bf16 (33792) U 4x{ekt,vt}[32][72]
    __shared__ float stats[640];       // [64][4][2] partials + [64][2] mu/rs

    const int b = blockIdx.y, tile = blockIdx.x, n0 = tile * 64;
    const int tid = threadIdx.x;
    const int w = tid >> 6, lane = tid & 63;
    const int lrow = lane & 15, kq = lane >> 4;
    bf16* A = (bf16*)smem;             // [64][264]

    // ---- stage x tile: float4 along n, LN partial stats ----
    {
        const int nq = tid & 15, cp = tid >> 4;    // n-quad, c-pair group
        float s[4] = {0.f,0.f,0.f,0.f}, sq[4] = {0.f,0.f,0.f,0.f};
        #pragma unroll
        for (int i = 0; i < 8; ++i) {
            int c0 = cp * 2 + 32 * i;
            const float* xp = x + ((size_t)b * CH + c0) * NPOS + n0 + nq * 4;
            float4 fa = *(const float4*)xp;
            float4 fb = *(const float4*)(xp + NPOS);
            #pragma unroll
            for (int j = 0; j < 4; ++j) {
                float va = (&fa.x)[j], vb = (&fb.x)[j];
                s[j] += va + vb; sq[j] += va * va + vb * vb;
                *(unsigned*)&A[(nq * 4 + j) * 264 + c0] =
                    (unsigned)f2us(va) | ((unsigned)f2us(vb) << 16);
            }
        }
        // reduce over the 4 cp-groups within this wave (lane bits 4,5)
        #pragma unroll
        for (int j = 0; j < 4; ++j) {
            s[j]  += __shfl_xor(s[j], 16, 64);  sq[j] += __shfl_xor(sq[j], 16, 64);
            s[j]  += __shfl_xor(s[j], 32, 64);  sq[j] += __shfl_xor(sq[j], 32, 64);
            if (lane < 16) {
                stats[(nq * 4 + j) * 8 + w * 2]     = s[j];
                stats[(nq * 4 + j) * 8 + w * 2 + 1] = sq[j];
            }
        }
    }
    __syncthreads();
    if (tid < 64) {
        float s  = stats[tid*8] + stats[tid*8+2] + stats[tid*8+4] + stats[tid*8+6];
        float sq = stats[tid*8+1] + stats[tid*8+3] + stats[tid*8+5] + stats[tid*8+7];
        float m = s * (1.f / 256.f);
        float var = sq * (1.f / 256.f) - m * m;
        stats[512 + tid * 2] = m;
        stats[512 + tid * 2 + 1] = rsqrtf(var + 1e-5f);
    }
    __syncthreads();
    {   // normalize A in place (u32 pairs)
        unsigned* A32 = (unsigned*)A;
        #pragma unroll 4
        for (int i = 0; i < 32; ++i) {
            int idx = i * 256 + tid;
            int c2 = idx & 127, n = idx >> 7;
            unsigned u = A32[n * 132 + c2];
            float m = stats[512 + n * 2], rs = stats[512 + n * 2 + 1];
            float v0 = (us2f((unsigned short)(u & 0xffffu)) - m) * rs;
            float v1 = (us2f((unsigned short)(u >> 16)) - m) * rs;
            A32[n * 132 + c2] = (unsigned)f2us(v0) | ((unsigned)f2us(v1) << 16);
        }
    }
    __syncthreads();   // A normalized; read-only until the v-phase barrier

    ushort4 ekp[4][2];                 // exp(k) bf16-packed, lives k-phase -> v-phase
    float se0 = 0.f, se1 = 0.f;

    for (int ph = 0; ph < 3; ++ph) {   // q, k, v
        const bf16* wp = wqb + (size_t)(ph * 128 + w * 32) * 256;
        f32x4 acc[4][2];
        #pragma unroll
        for (int i = 0; i < 4; ++i) {
            acc[i][0] = (f32x4){0.f,0.f,0.f,0.f};
            acc[i][1] = (f32x4){0.f,0.f,0.f,0.f};
        }
        #pragma unroll 2
        for (int k0 = 0; k0 < 256; k0 += 32) {
            bf8v af[4], bfr[2];
            #pragma unroll
            for (int t = 0; t < 4; ++t)
                af[t] = *(const bf8v*)&A[(t * 16 + lrow) * 264 + k0 + kq * 8];
            #pragma unroll
            for (int t = 0; t < 2; ++t)
                bfr[t] = *(const bf8v*)&wp[(size_t)(t * 16 + lrow) * 256 + k0 + kq * 8];
            #pragma unroll
            for (int mt = 0; mt < 4; ++mt)
                #pragma unroll
                for (int nt = 0; nt < 2; ++nt)
                    acc[mt][nt] = __builtin_amdgcn_mfma_f32_16x16x32_bf16(
                        af[mt], bfr[nt], acc[mt][nt], 0, 0, 0);
        }

        if (ph == 0) {
            // q softmax (in-register, head == wave) + packed u32 p store
            unsigned* pg32 = (unsigned*)p;
            #pragma unroll
            for (int mt = 0; mt < 4; ++mt)
                #pragma unroll
                for (int r = 0; r < 4; ++r) {
                    float e0 = __expf(b2f(f2b(acc[mt][0][r])));
                    float e1 = __expf(b2f(f2b(acc[mt][1][r])));
                    float s = e0 + e1;
                    s += __shfl_xor(s, 1, 64);  s += __shfl_xor(s, 2, 64);
                    s += __shfl_xor(s, 4, 64);  s += __shfl_xor(s, 8, 64);
                    float rd = 1.f / s;
                    int row = mt * 16 + kq * 4 + r;
                    pg32[(size_t)(b * NPOS + n0 + row) * 64 + w * 16 + lrow] =
                        (unsigned)f2us(e0 * rd) | ((unsigned)f2us(e1 * rd) << 16);
                }
        } else if (ph == 1) {
            // exp(k) -> bf16 pack (kept in regs); sumexp partials from the
            // SAME rounded values (so ctx/se rounding cancels)
            se0 = 0.f; se1 = 0.f;
            #pragma unroll
            for (int mt = 0; mt < 4; ++mt) {
                ushort4 u0, u1;
                unsigned short q_;
                #pragma unroll
                for (int r = 0; r < 4; ++r) {
                    q_ = f2us(__expf(b2f(f2b(acc[mt][0][r]))));
                    se0 += us2f(q_); (&u0.x)[r] = q_;
                    q_ = f2us(__expf(b2f(f2b(acc[mt][1][r]))));
                    se1 += us2f(q_); (&u1.x)[r] = q_;
                }
                ekp[mt][0] = u0; ekp[mt][1] = u1;
            }
            se0 += __shfl_xor(se0, 16, 64); se0 += __shfl_xor(se0, 32, 64);
            se1 += __shfl_xor(se1, 16, 64); se1 += __shfl_xor(se1, 32, 64);
        } else {
            // v phase done: A is dead after this barrier
            __syncthreads();
            bf16* ekt = (bf16*)(smem + w * 9216);          // [32][72] head w
            bf16* vt  = (bf16*)(smem + w * 9216 + 4608);   // [32][72]
            #pragma unroll
            for (int mt = 0; mt < 4; ++mt)
                #pragma unroll
                for (int nt = 0; nt < 2; ++nt) {
                    ushort4 vv;
                    vv.x = f2us(acc[mt][nt][0]); vv.y = f2us(acc[mt][nt][1]);
                    vv.z = f2us(acc[mt][nt][2]); vv.w = f2us(acc[mt][nt][3]);
                    int d = nt * 16 + lrow, n = mt * 16 + kq * 4;
                    *(ushort4*)&vt[d * 72 + n]  = vv;
                    *(ushort4*)&ekt[d * 72 + n] = ekp[mt][nt];
                }
            // ctx partial: D[d][e] = sum_n ekt[d][n]*vt[e][n]  (per-wave data)
            f32x4 cacc[2][2];
            cacc[0][0] = (f32x4){0.f,0.f,0.f,0.f}; cacc[0][1] = cacc[0][0];
            cacc[1][0] = cacc[0][0];               cacc[1][1] = cacc[0][0];
            #pragma unroll
            for (int ks = 0; ks < 2; ++ks) {
                bf8v a2[2], bv2[2];
                a2[0]  = *(const bf8v*)&ekt[lrow * 72 + ks * 32 + kq * 8];
                a2[1]  = *(const bf8v*)&ekt[(16 + lrow) * 72 + ks * 32 + kq * 8];
                bv2[0] = *(const bf8v*)&vt[lrow * 72 + ks * 32 + kq * 8];
                bv2[1] = *(const bf8v*)&vt[(16 + lrow) * 72 + ks * 32 + kq * 8];
                #pragma unroll
                for (int mt2 = 0; mt2 < 2; ++mt2)
                    #pragma unroll
                    for (int nt2 = 0; nt2 < 2; ++nt2)
                        cacc[mt2][nt2] = __builtin_amdgcn_mfma_f32_16x16x32_bf16(
                            a2[mt2], bv2[nt2], cacc[mt2][nt2], 0, 0, 0);
            }
            float* pb = ctxp + ((size_t)(b * 64 + tile) * 4 + w) * 1056;
            #pragma unroll
            for (int mt2 = 0; mt2 < 2; ++mt2)
                #pragma unroll
                for (int nt2 = 0; nt2 < 2; ++nt2)
                    #pragma unroll
                    for (int r = 0; r < 4; ++r) {
                        int d = mt2 * 16 + kq * 4 + r, e = nt2 * 16 + lrow;
                        pb[d * 32 + e] = cacc[mt2][nt2][r];
                    }
            if (kq == 0) {
                pb[1024 + lrow] = se0;
                pb[1024 + 16 + lrow] = se1;
            }
        }
    }
}

// ---------------------------------------------------------------------------
// K2': sum the 64 per-tile context partials -> ctxu[b][h][1024], separt[b][h][32]
// 17.3 MB read (L3-resident), 270 KB written. grid (4 h, 16 b).
// ---------------------------------------------------------------------------
__global__ __launch_bounds__(256)
void reduce_ctx_kernel(const float* __restrict__ ctxp, float* __restrict__ ctxu,
                       float* __restrict__ separt) {
    int h = blockIdx.x, b = blockIdx.y;
    int tid = threadIdx.x;
    for (int i = 0; i < 2; ++i) {
        int idx = i * 256 + tid;           // f32x4 index, 264 per (b,h)
        if (idx >= 264) break;
        f32x4 s = (f32x4){0.f,0.f,0.f,0.f};
        for (int t = 0; t < 64; ++t) {
            const float* src = ctxp + ((size_t)(b * 64 + t) * 4 + h) * 1056 + idx * 4;
            s += *(const f32x4*)src;
        }
        int j = idx * 4;
        if (j < 1024) *(f32x4*)&ctxu[((size_t)(b * 4 + h)) * 1024 + j] = s;
        else          *(f32x4*)&separt[((size_t)(b * 4 + h)) * 32 + (j - 1024)] = s;
    }
}

// ---------------------------------------------------------------------------
// K3: wmod_b[c][pi(h,d)] = (sum_e Wout[c][h*32+e]*ctx[h][d][e]) / se[h,d] / (N*sqrt32)
// store permuted with pi(d) = (d&15)*2 + (d>>4) to match p's packed layout.
// ---------------------------------------------------------------------------
__global__ __launch_bounds__(256)
void wmod_kernel(const float* __restrict__ Wout, const float* __restrict__ ctxu,
                 const float* __restrict__ separt, bf16* __restrict__ wmod) {
    __shared__ float cs[4096];
    __shared__ float ses[128];
    int cg = blockIdx.x, b = blockIdx.y;
    int tid = threadIdx.x;
    for (int idx = tid; idx < 4096; idx += 256) {
        int hh = idx >> 10, rest = idx & 1023;
        cs[idx] = ctxu[((size_t)(b * 4 + hh)) * 1024 + rest];
    }
    if (tid < 128) {
        int hh = tid >> 5, d = tid & 31;
        ses[tid] = separt[((size_t)(b * 4 + hh)) * 32 + d];
    }
    __syncthreads();
    int c = cg * 32 + (tid & 31);
    int g = tid >> 5;
    int h = g >> 1, d0 = (g & 1) * 16;
    const float* wr = Wout + (size_t)c * INNER + h * DH;
    float w[32];
    #pragma unroll
    for (int i = 0; i < 8; ++i) {
        float4 t = *(const float4*)&wr[i * 4];
        w[i * 4] = t.x; w[i * 4 + 1] = t.y; w[i * 4 + 2] = t.z; w[i * 4 + 3] = t.w;
    }
    const float SCALE = 4.3158341e-05f;   // 1/(4096*sqrt(32))
    #pragma unroll
    for (int dd = 0; dd < 16; ++dd) {
        int d = d0 + dd;
        const float* cr = &cs[h * 1024 + d * 32];
        float s = 0.f;
        #pragma unroll
        for (int e4 = 0; e4 < 8; ++e4) {
            f32x4 t = *(const f32x4*)&cr[e4 * 4];
            s += w[e4 * 4] * t[0] + w[e4 * 4 + 1] * t[1]
               + w[e4 * 4 + 2] * t[2] + w[e4 * 4 + 3] * t[3];
        }
        float val = s * SCALE / ses[h * 32 + d];
        wmod[((size_t)b * CH + c) * INNER + h * DH + ((d & 15) * 2 + (d >> 4))] =
            f2b(val);
    }
}

// ---------------------------------------------------------------------------
// K4: fused y-GEMM + bias + channel LN + residual. 64-row n-tiles.
// p staged via uint4; residual epilogue via float4 (ct padded to [256][36]).
// ---------------------------------------------------------------------------
__global__ __launch_bounds__(256)
void fused_out_kernel(const bf16* __restrict__ p, const bf16* __restrict__ wmod,
                      const float* __restrict__ bout, const float* __restrict__ x,
                      float* __restrict__ out) {
    __shared__ char lds[39424];
    bf16* Ap = (bf16*)lds;                 // [64][136] = 17408 B (union: ct)
    float* ct = (float*)lds;               // [256][36] f32 = 36864 B
    float* st = (float*)(lds + 36864);     // 640 floats

    const int b = blockIdx.y, n0 = blockIdx.x * 64;
    const int tid = threadIdx.x;
    const int w = tid >> 6, lane = tid & 63;
    const int lrow = lane & 15, kq = lane >> 4;

    // stage Ap = p tile [64][128] via uint4
    {
        const uint4* pg = (const uint4*)p;
        unsigned* A32 = (unsigned*)Ap;
        #pragma unroll
        for (int i = 0; i < 4; ++i) {
            int idx = i * 256 + tid;
            int c4 = idx & 15, n = idx >> 4;
            uint4 u = pg[(size_t)(b * NPOS + n0 + n) * 16 + c4];
            *(uint4*)(A32 + n * 68 + c4 * 4) = u;
        }
    }
    __syncthreads();

    f32x4 acc[4][4];
    #pragma unroll
    for (int i = 0; i < 4; ++i)
        #pragma unroll
        for (int j = 0; j < 4; ++j) acc[i][j] = (f32x4){0.f, 0.f, 0.f, 0.f};

    const bf16* wb = wmod + (size_t)b * CH * INNER + (size_t)(w * 64) * INNER;
    #pragma unroll 2
    for (int k0 = 0; k0 < 128; k0 += 32) {
        bf8v af[4], bfr[4];
        #pragma unroll
        for (int t = 0; t < 4; ++t)
            af[t] = *(const bf8v*)&Ap[(t * 16 + lrow) * 136 + k0 + kq * 8];
        #pragma unroll
        for (int t = 0; t < 4; ++t)
            bfr[t] = *(const bf8v*)&wb[(size_t)(t * 16 + lrow) * 128 + k0 + kq * 8];
        #pragma unroll
        for (int mt = 0; mt < 4; ++mt)
            #pragma unroll
            for (int nt = 0; nt < 4; ++nt)
                acc[mt][nt] = __builtin_amdgcn_mfma_f32_16x16x32_bf16(
                    af[mt], bfr[nt], acc[mt][nt], 0, 0, 0);
    }

    // bias add (before LN, matches reference)
    #pragma unroll
    for (int nt = 0; nt < 4; ++nt) {
        float bv = bout[w * 64 + nt * 16 + lrow];
        #pragma unroll
        for (int mt = 0; mt < 4; ++mt)
            #pragma unroll
            for (int r = 0; r < 4; ++r) acc[mt][nt][r] += bv;
    }

    // LN stats: per (mt,r) row, partial over this wave's 64 cols
    #pragma unroll
    for (int mt = 0; mt < 4; ++mt)
        #pragma unroll
        for (int r = 0; r < 4; ++r) {
            float s = 0.f, sq = 0.f;
            #pragma unroll
            for (int nt = 0; nt < 4; ++nt) {
                float v = acc[mt][nt][r];
                s += v; sq += v * v;
            }
            #pragma unroll
            for (int m = 1; m <= 8; m <<= 1) {
                s += __shfl_xor(s, m, 64);
                sq += __shfl_xor(sq, m, 64);
            }
            if (lrow == 0) {
                int row = mt * 16 + kq * 4 + r;
                st[w * 128 + row * 2] = s;
                st[w * 128 + row * 2 + 1] = sq;
            }
        }
    __syncthreads();
    if (tid < 64) {
        float s  = st[tid * 2]       + st[128 + tid * 2]
                 + st[256 + tid * 2] + st[384 + tid * 2];
        float sq = st[tid * 2 + 1]       + st[128 + tid * 2 + 1]
                 + st[256 + tid * 2 + 1] + st[384 + tid * 2 + 1];
        float m = s * (1.f / 256.f);
        float var = sq * (1.f / 256.f) - m * m;
        st[512 + tid * 2] = m;
        st[512 + tid * 2 + 1] = rsqrtf(var + 1e-5f);
    }
    __syncthreads();
    // normalize accs in place
    #pragma unroll
    for (int mt = 0; mt < 4; ++mt)
        #pragma unroll
        for (int r = 0; r < 4; ++r) {
            int row = mt * 16 + kq * 4 + r;
            float m = st[512 + row * 2], rs = st[512 + row * 2 + 1];
            #pragma unroll
            for (int nt = 0; nt < 4; ++nt)
                acc[mt][nt][r] = (acc[mt][nt][r] - m) * rs;
        }

    // 2 output chunks of 32 rows: LDS transpose -> float4 store + residual
    for (int pr = 0; pr < 2; ++pr) {
        __syncthreads();
        #pragma unroll
        for (int mi = 0; mi < 2; ++mi) {
            int mt = pr * 2 + mi;
            #pragma unroll
            for (int nt = 0; nt < 4; ++nt)
                #pragma unroll
                for (int r = 0; r < 4; ++r) {
                    int rl = mi * 16 + kq * 4 + r;
                    ct[(w * 64 + nt * 16 + lrow) * 36 + rl] = acc[mt][nt][r];
                }
        }
        __syncthreads();
        #pragma unroll
        for (int i = 0; i < 8; ++i) {
            int idx = i * 256 + tid;       // 2048 float4
            int n4 = (idx & 7) * 4, c = idx >> 3;
            size_t gi = ((size_t)b * CH + c) * NPOS + n0 + pr * 32 + n4;
            f32x4 cv = *(const f32x4*)&ct[c * 36 + n4];
            float4 xv = *(const float4*)&x[gi];
            float4 ov;
            ov.x = cv[0] + xv.x; ov.y = cv[1] + xv.y;
            ov.z = cv[2] + xv.z; ov.w = cv[3] + xv.w;
            *(float4*)&out[gi] = ov;
        }
    }
}

// ---------------------------------------------------------------------------
extern "C" void kernel_launch(void* const* d_in, const int* in_sizes, int n_in,
                              void* d_out, int out_size, void* d_ws, size_t ws_size,
                              hipStream_t stream) {
    const float* x    = (const float*)d_in[0];   // [16,256,64,64]
    const float* Wqkv = (const float*)d_in[1];   // [384,256]
    const float* Wout = (const float*)d_in[2];   // [256,128]
    const float* bout = (const float*)d_in[3];   // [256]
    float* out = (float*)d_out;

    // workspace (~35.6 MB)
    char* ws = (char*)d_ws;
    bf16*  p      = (bf16*)ws;                       // 16*4096*128*2   = 16777216
    float* ctxp   = (float*)(ws + 16777216);         // 16*64*4*1056*4  = 17301504
    float* ctxu   = (float*)(ws + 34078720);         // 16*4*1024*4     = 262144
    float* separt = (float*)(ws + 34340864);         // 16*4*32*4       = 8192
    bf16*  wmod   = (bf16*)(ws + 34349056);          // 16*256*128*2    = 1048576
    bf16*  wqb    = (bf16*)(ws + 35397632);          // 384*256*2       = 196608

    prep_w_kernel<<<dim3(96), 256, 0, stream>>>(Wqkv, wqb);
    fused_qkv_kernel<<<dim3(64, BATCH), 256, 0, stream>>>(x, wqb, p, ctxp);
    reduce_ctx_kernel<<<dim3(4, BATCH), 256, 0, stream>>>(ctxp, ctxu, separt);
    wmod_kernel<<<dim3(8, BATCH), 256, 0, stream>>>(Wout, ctxu, separt, wmod);
    fused_out_kernel<<<dim3(64, BATCH), 256, 0, stream>>>(p, wmod, bout, x, out);
}